// Round 1
// baseline (5334.433 us; speedup 1.0000x reference)
//
#include <hip/hip_runtime.h>
#include <hip/hip_bf16.h>
#include <math.h>

typedef __attribute__((ext_vector_type(8))) short bf16x8;
typedef __attribute__((ext_vector_type(4))) float f32x4;
typedef __attribute__((ext_vector_type(4))) int i32x4;

#define TT 1024
#define BB 128
#define II 256
#define SS 512
#define OUT_T 1025
#define OUT_BSTRIDE ((size_t)OUT_T * SS)   // 524800

// ---------- bf16 helpers ----------
static __device__ __forceinline__ unsigned short f2bf(float f) {
  union { float f; unsigned int u; } v; v.f = f;
  unsigned int r = v.u + 0x7fffu + ((v.u >> 16) & 1u);
  return (unsigned short)(r >> 16);
}
static __device__ __forceinline__ float bf2f(unsigned short h) {
  union { unsigned int u; float f; } v; v.u = ((unsigned int)h) << 16;
  return v.f;
}
static __device__ __forceinline__ bf16x8 pack8(const float* p) {
  float4 a = *(const float4*)p;
  float4 b = *(const float4*)(p + 4);
  bf16x8 r;
  r[0]=(short)f2bf(a.x); r[1]=(short)f2bf(a.y); r[2]=(short)f2bf(a.z); r[3]=(short)f2bf(a.w);
  r[4]=(short)f2bf(b.x); r[5]=(short)f2bf(b.y); r[6]=(short)f2bf(b.z); r[7]=(short)f2bf(b.w);
  return r;
}

// ---------- device-coherent (cross-XCD safe, cache-bypassing) ops ----------
static __device__ __forceinline__ i32x4 ld_coh_b128_issue(const void* p) {
  i32x4 r;
  asm volatile("global_load_dwordx4 %0, %1, off sc0 sc1" : "=v"(r) : "v"(p) : "memory");
  return r;
}
static __device__ __forceinline__ unsigned int ld_coh_b32(const void* p) {
  unsigned int r;
  asm volatile("global_load_dword %0, %1, off sc0 sc1\n\ts_waitcnt vmcnt(0)"
               : "=v"(r) : "v"(p) : "memory");
  return r;
}
static __device__ __forceinline__ void st_coh_b16(void* p, unsigned short v) {
  unsigned int vv = v;
  asm volatile("global_store_short %0, %1, off sc0 sc1" :: "v"(p), "v"(vv) : "memory");
}
static __device__ __forceinline__ void st_coh_b32(void* p, unsigned int v) {
  asm volatile("global_store_dword %0, %1, off sc0 sc1" :: "v"(p), "v"(v) : "memory");
}
static __device__ __forceinline__ void waitcnt_vm0() {
  asm volatile("s_waitcnt vmcnt(0)" ::: "memory");
}

// =====================================================================
// Phase 1: input projections.  proj[m][0:512)=x@B0w^T+b0, [512:1024)=x@B1w^T+b1,
// [1024:1536)=sigmoid(x@Gw^T+gb).  m = b*1024 + t.  Output bf16.
// =====================================================================
__global__ __launch_bounds__(256) void proj_kernel(
    const float* __restrict__ x,
    const float* __restrict__ B0w, const float* __restrict__ B0b,
    const float* __restrict__ B1w, const float* __restrict__ B1b,
    const float* __restrict__ Gw,  const float* __restrict__ Gb,
    unsigned short* __restrict__ proj)
{
  __shared__ unsigned short Ab[64 * 40];
  __shared__ unsigned short Bb[64 * 40];
  int bid = blockIdx.x;
  int nb = bid % 24, mb = bid / 24;
  int m0 = mb * 64, n0 = nb * 64;
  const float* Wp; const float* bp; bool isgate = false;
  if (n0 < 512)       { Wp = B0w + (size_t)n0 * II;          bp = B0b + n0; }
  else if (n0 < 1024) { Wp = B1w + (size_t)(n0 - 512) * II;  bp = B1b + (n0 - 512); }
  else                { Wp = Gw  + (size_t)(n0 - 1024) * II; bp = Gb + (n0 - 1024); isgate = true; }

  int tid = threadIdx.x;
  int lane = tid & 63, wid = tid >> 6;
  int r = tid >> 2, c = tid & 3;          // staging: row 0..63, k-chunk 0..3 (8 elems)
  int mt0 = (wid >> 1) * 2, nt0 = (wid & 1) * 2;

  f32x4 acc[2][2] = {};
  for (int k0 = 0; k0 < II; k0 += 32) {
    __syncthreads();     // previous iteration's reads done
    *(bf16x8*)&Ab[r * 40 + c * 8] = pack8(x  + (size_t)(m0 + r) * II + k0 + c * 8);
    *(bf16x8*)&Bb[r * 40 + c * 8] = pack8(Wp + (size_t)r * II       + k0 + c * 8);
    __syncthreads();
    bf16x8 af[2], bf[2];
#pragma unroll
    for (int mi = 0; mi < 2; ++mi)
      af[mi] = *(const bf16x8*)&Ab[((mt0 + mi) * 16 + (lane & 15)) * 40 + 8 * (lane >> 4)];
#pragma unroll
    for (int ni = 0; ni < 2; ++ni)
      bf[ni] = *(const bf16x8*)&Bb[((nt0 + ni) * 16 + (lane & 15)) * 40 + 8 * (lane >> 4)];
#pragma unroll
    for (int mi = 0; mi < 2; ++mi)
#pragma unroll
      for (int ni = 0; ni < 2; ++ni)
        acc[mi][ni] = __builtin_amdgcn_mfma_f32_16x16x32_bf16(af[mi], bf[ni], acc[mi][ni], 0, 0, 0);
  }
  // epilogue: bias (+ sigmoid for gate), store bf16
#pragma unroll
  for (int mi = 0; mi < 2; ++mi)
#pragma unroll
    for (int ni = 0; ni < 2; ++ni)
#pragma unroll
      for (int q = 0; q < 4; ++q) {
        int m  = m0 + (mt0 + mi) * 16 + (lane >> 4) * 4 + q;
        int nl = (nt0 + ni) * 16 + (lane & 15);
        float v = acc[mi][ni][q] + bp[nl];
        if (isgate) v = 1.0f / (1.0f + expf(-v));
        proj[(size_t)m * 1536 + n0 + nl] = f2bf(v);
      }
}

// =====================================================================
// Phase 2: persistent recurrence. 64 blocks = 8 batch-groups x 8 state-slices.
// Block (g = bid&7, j = bid>>3): rows b0=g*16..+15, cols c0=j*64..+63.
// A0/A1 column-slices resident in LDS (bf16). Cross-block state exchange via
// ping-pong bf16 buffer with sc0/sc1 ops + per-block step flags.
// =====================================================================
__global__ __launch_bounds__(256) void recur_kernel(
    const float* __restrict__ s0,
    const float* __restrict__ A0w, const float* __restrict__ A1w,
    const unsigned short* __restrict__ proj,
    const float* __restrict__ alpha_p, const int* __restrict__ z_p,
    unsigned short* state_bf,          // [2][128][512] bf16
    unsigned int* flags,               // [8 groups][8 slices]
    float* __restrict__ out)           // [128][1025][512]
{
  extern __shared__ unsigned short lds[];
  unsigned short* As0 = lds;                 // [64][520]
  unsigned short* As1 = lds + 64 * 520;      // [64][520]
  unsigned short* Ss  = lds + 2 * 64 * 520;  // [16][520]

  int bid = blockIdx.x;
  int g = bid & 7, j = bid >> 3;
  int b0 = g * 16, c0 = j * 64;
  int tid = threadIdx.x, lane = tid & 63, wid = tid >> 6;
  float alpha = *alpha_p; int z = *z_p;
  float om_alpha = 1.0f - alpha;

  // load resident A slices (rows c0..c0+63 of A0w/A1w), fp32 -> bf16
  for (int e = tid; e < 64 * 64; e += 256) {
    int nl = e >> 6, kc = e & 63;
    *(bf16x8*)&As0[nl * 520 + kc * 8] = pack8(A0w + (size_t)(c0 + nl) * SS + kc * 8);
    *(bf16x8*)&As1[nl * 520 + kc * 8] = pack8(A1w + (size_t)(c0 + nl) * SS + kc * 8);
  }

  int rowbase = (lane >> 4) * 4;
  int colw = c0 + wid * 16 + (lane & 15);    // this lane's global state col

  // s_prev (fp32 carry) from s0; write t=0 output
  float sprev[4];
#pragma unroll
  for (int q = 0; q < 4; ++q) {
    int gb = b0 + rowbase + q;
    sprev[q] = s0[(size_t)gb * SS + colw];
    out[(size_t)gb * OUT_BSTRIDE + colw] = sprev[q];
  }

  for (int t = 0; t < TT; ++t) {
    // ---- acquire state t into Ss ----
    if (t == 0) {
#pragma unroll
      for (int c2 = 0; c2 < 4; ++c2) {
        int e = tid + 256 * c2;              // 0..1023 = 16 rows x 64 chunks
        int rr = e >> 6, kc = e & 63;
        *(bf16x8*)&Ss[rr * 520 + kc * 8] = pack8(s0 + (size_t)(b0 + rr) * SS + kc * 8);
      }
    } else {
      if (tid < 8) {
        const unsigned int* fp = flags + g * 8 + tid;
        while (ld_coh_b32(fp) < (unsigned int)t) { }
      }
      __syncthreads();
      const unsigned short* sb = state_bf + (size_t)(t & 1) * BB * SS + (size_t)b0 * SS;
      i32x4 v[4];
#pragma unroll
      for (int c2 = 0; c2 < 4; ++c2) {
        int e = tid + 256 * c2;
        int rr = e >> 6, kc = e & 63;
        v[c2] = ld_coh_b128_issue(sb + rr * SS + kc * 8);
      }
      waitcnt_vm0();
#pragma unroll
      for (int c2 = 0; c2 < 4; ++c2) {
        int e = tid + 256 * c2;
        int rr = e >> 6, kc = e & 63;
        *(bf16x8*)&Ss[rr * 520 + kc * 8] = *(bf16x8*)&v[c2];
      }
    }
    __syncthreads();

    // ---- u0,u1 = S @ A0slice^T, S @ A1slice^T  (16x16 tile per wave) ----
    f32x4 acc0 = {0.f, 0.f, 0.f, 0.f}, acc1 = {0.f, 0.f, 0.f, 0.f};
    const unsigned short* ap  = Ss  + (lane & 15) * 520 + 8 * (lane >> 4);
    const unsigned short* bp0 = As0 + (wid * 16 + (lane & 15)) * 520 + 8 * (lane >> 4);
    const unsigned short* bp1 = As1 + (wid * 16 + (lane & 15)) * 520 + 8 * (lane >> 4);
#pragma unroll
    for (int kk = 0; kk < 16; ++kk) {
      bf16x8 af  = *(const bf16x8*)(ap  + kk * 32);
      bf16x8 b0f = *(const bf16x8*)(bp0 + kk * 32);
      bf16x8 b1f = *(const bf16x8*)(bp1 + kk * 32);
      acc0 = __builtin_amdgcn_mfma_f32_16x16x32_bf16(af, b0f, acc0, 0, 0, 0);
      acc1 = __builtin_amdgcn_mfma_f32_16x16x32_bf16(af, b1f, acc1, 0, 0, 0);
    }

    // ---- elementwise: f = (1-a)tanh(u0+bx0)+a*tanh(u1+bx1); s = g f + (1-g) s ----
    unsigned short* st_next = state_bf + (size_t)((t + 1) & 1) * BB * SS;
#pragma unroll
    for (int q = 0; q < 4; ++q) {
      int gb = b0 + rowbase + q;
      size_t pbase = ((size_t)gb * TT + t) * 1536;
      float bx0 = bf2f(proj[pbase + colw]);
      float bx1 = bf2f(proj[pbase + 512 + colw]);
      float gg  = bf2f(proj[pbase + 1024 + colw]);
      float f0 = tanhf(acc0[q] + bx0);
      float f;
      if (z != 0) {
        float f1 = tanhf(acc1[q] + bx1);
        f = om_alpha * f0 + alpha * f1;
      } else {
        f = f0;
      }
      float sn = gg * f + (1.0f - gg) * sprev[q];
      sprev[q] = sn;
      out[(size_t)gb * OUT_BSTRIDE + (size_t)(t + 1) * SS + colw] = sn;
      st_coh_b16(st_next + (size_t)gb * SS + colw, f2bf(sn));
    }
    waitcnt_vm0();       // all my coherent stores retired (reached coherence point)
    __syncthreads();     // whole block done with step t (incl. LDS reads)
    if (tid == 0) st_coh_b32(flags + g * 8 + j, (unsigned int)(t + 1));
  }
}

// =====================================================================
extern "C" void kernel_launch(void* const* d_in, const int* in_sizes, int n_in,
                              void* d_out, int out_size, void* d_ws, size_t ws_size,
                              hipStream_t stream) {
  const float* x   = (const float*)d_in[0];
  const float* s0  = (const float*)d_in[1];
  const float* A0w = (const float*)d_in[2];
  const float* B0w = (const float*)d_in[3];
  const float* B0b = (const float*)d_in[4];
  const float* A1w = (const float*)d_in[5];
  const float* B1w = (const float*)d_in[6];
  const float* B1b = (const float*)d_in[7];
  const float* Gw  = (const float*)d_in[8];
  const float* Gb  = (const float*)d_in[9];
  const float* alp = (const float*)d_in[10];
  const int*   zp  = (const int*)d_in[11];
  float* out = (float*)d_out;

  char* ws = (char*)d_ws;
  size_t proj_bytes  = (size_t)BB * TT * 1536 * 2;        // 402,653,184
  size_t state_off   = proj_bytes;
  size_t state_bytes = (size_t)2 * BB * SS * 2;           // 262,144
  size_t flag_off    = state_off + state_bytes;
  unsigned short* proj     = (unsigned short*)(ws);
  unsigned short* state_bf = (unsigned short*)(ws + state_off);
  unsigned int*   flags    = (unsigned int*)(ws + flag_off);

  hipMemsetAsync(flags, 0, 64 * sizeof(unsigned int), stream);

  proj_kernel<<<dim3((131072 / 64) * (1536 / 64)), dim3(256), 0, stream>>>(
      x, B0w, B0b, B1w, B1b, Gw, Gb, proj);

  size_t lds_bytes = (size_t)(2 * 64 * 520 + 16 * 520) * 2;   // 149,760 B
  hipFuncSetAttribute((const void*)recur_kernel,
                      hipFuncAttributeMaxDynamicSharedMemorySize, (int)lds_bytes);
  recur_kernel<<<dim3(64), dim3(256), lds_bytes, stream>>>(
      s0, A0w, A1w, proj, alp, zp, state_bf, flags, out);
}